// Round 4
// baseline (163.855 us; speedup 1.0000x reference)
//
#include <hip/hip_runtime.h>

// B=2048, T=128, I=130, H=10, 3H=30, D1=20
// Two-phase design:
//   Phase 1 (xi_gemm): xi[row][g] = Wih[g,:].x_row + bih[g] for all 524288
//     rows (2 GRUs x B x T), row-major into d_ws (63 MB). No recurrence ->
//     fully pipelined, 8192 waves. Gate-parallel: lane=(g<32, half), wih
//     row-half hoisted to 65 VGPRs, x row staged to per-wave LDS.
//   Phase 2 (gru_scan): serial scan, 2 chains/wave, lane k<10 per chain
//     computes ALL THREE of its gates (r,z,n) itself: one LDS h-roundtrip
//     per step (vs 3 in the monolithic kernel), xi streamed with 2-deep
//     prefetch (L2/L3-hot). MLP tail fused via v = W2@W1, atomicAdd.
// Fallback: monolithic round-3 kernel if ws_size < 63 MB.

#define BB 2048
#define TT 128
#define II 130
#define ROWS_PER_GRU (BB * TT)          // 262144
#define ROWS_TOTAL   (2 * ROWS_PER_GRU) // 524288

__device__ __forceinline__ float sigmoidf_fast(float x) {
    return __fdividef(1.f, 1.f + __expf(-x));
}
__device__ __forceinline__ float tanhf_fast(float x) {
    float ax = fabsf(x);
    float e = __expf(-2.f * ax);
    float t = __fdividef(1.f - e, 1.f + e);
    return copysignf(t, x);
}

// ---------------- Phase 1: input projection GEMM ----------------
__global__ __launch_bounds__(256, 4)
void xi_gemm(const float* __restrict__ ru, const float* __restrict__ en,
             const float* __restrict__ ruWih, const float* __restrict__ rubih,
             const float* __restrict__ enWih, const float* __restrict__ enbih,
             float* __restrict__ xi)
{
    const int tid  = threadIdx.x;
    const int wv   = tid >> 6;
    const int lane = tid & 63;
    const int g    = lane & 31;        // gate 0..29 active
    const int h    = lane >> 5;        // K-half
    const int w    = blockIdx.x * 4 + wv;       // wave id 0..8191
    const int gru  = (w >= 4096);
    const long row0 = (long)w * 64;             // 64 rows per wave

    const float* __restrict__ x   = gru ? en    : ru;
    const float* __restrict__ Wih = gru ? enWih : ruWih;
    const float* __restrict__ bih = gru ? enbih : rubih;

    const int gq = (g < 30) ? g : 0;
    float wih[64];
    #pragma unroll
    for (int j = 0; j < 64; ++j) wih[j] = Wih[gq * II + h * 64 + j];
    const float w_e  = Wih[gq * II + 128 + h];
    const float bihg = bih[gq];

    __shared__ __align__(16) float lds[4][132];
    float* __restrict__ X = lds[wv];

    const long r0l = row0 - (long)gru * ROWS_PER_GRU;  // local row in this gru
    const float* __restrict__ xrow = x + r0l * II;
    float* __restrict__ xo = xi + row0 * 30;

    // prefetch first row
    float xa = xrow[lane];
    float xb = xrow[64 + lane];
    float xc = (lane < 2) ? xrow[128 + lane] : 0.f;

    for (int i = 0; i < 64; ++i) {
        X[lane] = xa;
        X[64 + lane] = xb;
        if (lane < 2) X[128 + lane] = xc;

        {   // prefetch next row (clamped re-read on last iter)
            const int inext = (i < 63) ? i + 1 : i;
            const float* __restrict__ xn = xrow + (long)inext * II;
            xa = xn[lane];
            xb = xn[64 + lane];
            xc = (lane < 2) ? xn[128 + lane] : 0.f;
        }

        float s0 = 0.f, s1 = 0.f, s2 = 0.f, s3 = 0.f;
        const float4* __restrict__ xb4 = (const float4*)(X + h * 64);
        #pragma unroll
        for (int c = 0; c < 16; ++c) {
            const float4 v = xb4[c];
            s0 = fmaf(wih[4 * c + 0], v.x, s0);
            s1 = fmaf(wih[4 * c + 1], v.y, s1);
            s2 = fmaf(wih[4 * c + 2], v.z, s2);
            s3 = fmaf(wih[4 * c + 3], v.w, s3);
        }
        float s = (s0 + s1) + (s2 + s3);
        s = fmaf(w_e, X[128 + h], s);
        s += __shfl_xor(s, 32);          // combine K-halves

        if (lane < 30) xo[(long)i * 30 + lane] = s + bihg;   // coalesced 120B
    }
}

// ---------------- Phase 2: recurrent scan ----------------
__global__ __launch_bounds__(256, 4)
void gru_scan(const float* __restrict__ xi,
              const float* __restrict__ ruWhh, const float* __restrict__ rubhh,
              const float* __restrict__ enWhh, const float* __restrict__ enbhh,
              const float* __restrict__ W1, const float* __restrict__ b1,
              const float* __restrict__ W2, const float* __restrict__ b2,
              float* __restrict__ out)
{
    const int tid  = threadIdx.x;
    const int wv   = tid >> 6;
    const int lane = tid & 63;
    const int c    = lane >> 5;        // chain slot in wave (0/1)
    const int k    = lane & 31;        // hidden index, 0..9 active
    const int kq   = (k < 10) ? k : 0;
    const int chain = (blockIdx.x * 4 + wv) * 2 + c;   // 0..4095
    const int gru   = chain >> 11;
    const int b     = chain & (BB - 1);

    const float* __restrict__ Whh = gru ? enWhh : ruWhh;
    const float* __restrict__ bhh = gru ? enbhh : rubhh;

    // lane k owns gates k (r), 10+k (z), 20+k (n)
    float whhR[10], whhZ[10], whhN[10];
    #pragma unroll
    for (int j = 0; j < 10; ++j) {
        whhR[j] = Whh[kq * 10 + j];
        whhZ[j] = Whh[(10 + kq) * 10 + j];
        whhN[j] = Whh[(20 + kq) * 10 + j];
    }
    const float bR = bhh[kq], bZ = bhh[10 + kq], bN = bhh[20 + kq];

    __shared__ __align__(16) float lds[4][32];
    float* __restrict__ H = lds[wv] + c * 16;
    if (k < 12) H[k] = 0.f;            // h0 = 0 (in-order DS within wave)
    float hown = 0.f;

    const float* __restrict__ xrow =
        xi + ((long)gru * ROWS_PER_GRU + (long)b * TT) * 30;

    // 2-deep prefetch of this lane's three xi values
    float xR0 = xrow[kq],      xZ0 = xrow[10 + kq],  xN0 = xrow[20 + kq];
    float xR1 = xrow[30 + kq], xZ1 = xrow[40 + kq],  xN1 = xrow[50 + kq];

    for (int t = 0; t < TT; ++t) {
        const float xR = xR0, xZ = xZ0, xN = xN0;
        xR0 = xR1; xZ0 = xZ1; xN0 = xN1;
        {
            const int tn = (t + 2 < TT) ? t + 2 : TT - 1;
            const float* __restrict__ xp = xrow + (long)tn * 30;
            xR1 = xp[kq]; xZ1 = xp[10 + kq]; xN1 = xp[20 + kq];
        }

        const float4 h03 = *(const float4*)(H);
        const float4 h47 = *(const float4*)(H + 4);
        const float2 h89 = *(const float2*)(H + 8);

        float gr = bR, gz = bZ, gn = bN;      // 3 independent fma chains
        gr = fmaf(whhR[0], h03.x, gr); gz = fmaf(whhZ[0], h03.x, gz); gn = fmaf(whhN[0], h03.x, gn);
        gr = fmaf(whhR[1], h03.y, gr); gz = fmaf(whhZ[1], h03.y, gz); gn = fmaf(whhN[1], h03.y, gn);
        gr = fmaf(whhR[2], h03.z, gr); gz = fmaf(whhZ[2], h03.z, gz); gn = fmaf(whhN[2], h03.z, gn);
        gr = fmaf(whhR[3], h03.w, gr); gz = fmaf(whhZ[3], h03.w, gz); gn = fmaf(whhN[3], h03.w, gn);
        gr = fmaf(whhR[4], h47.x, gr); gz = fmaf(whhZ[4], h47.x, gz); gn = fmaf(whhN[4], h47.x, gn);
        gr = fmaf(whhR[5], h47.y, gr); gz = fmaf(whhZ[5], h47.y, gz); gn = fmaf(whhN[5], h47.y, gn);
        gr = fmaf(whhR[6], h47.z, gr); gz = fmaf(whhZ[6], h47.z, gz); gn = fmaf(whhN[6], h47.z, gn);
        gr = fmaf(whhR[7], h47.w, gr); gz = fmaf(whhZ[7], h47.w, gz); gn = fmaf(whhN[7], h47.w, gn);
        gr = fmaf(whhR[8], h89.x, gr); gz = fmaf(whhZ[8], h89.x, gz); gn = fmaf(whhN[8], h89.x, gn);
        gr = fmaf(whhR[9], h89.y, gr); gz = fmaf(whhZ[9], h89.y, gz); gn = fmaf(whhN[9], h89.y, gn);

        const float r = sigmoidf_fast(xR + gr);
        const float z = sigmoidf_fast(xZ + gz);
        const float n = tanhf_fast(xN + r * gn);
        const float hnew = fmaf(z, hown - n, n);   // (1-z)n + z*h
        hown = hnew;
        if (k < 10) H[k] = hnew;                   // one LDS roundtrip/step
    }

    // ---- fused MLP tail ----
    float val = 0.f;
    if (k < 10) {
        float v = 0.f;
        #pragma unroll
        for (int d = 0; d < 20; ++d)
            v = fmaf(W2[d], W1[d * 20 + gru * 10 + k], v);
        val = v * hown;
        if (k == 0 && gru == 0) {
            float c0 = b2[0];
            #pragma unroll
            for (int d = 0; d < 20; ++d) c0 = fmaf(W2[d], b1[d], c0);
            val += c0;
        }
    }
    val += __shfl_xor(val, 8);
    val += __shfl_xor(val, 4);
    val += __shfl_xor(val, 2);
    val += __shfl_xor(val, 1);
    if (k == 0) atomicAdd(&out[b], val);   // 2 commutative adds per output
}

// ---------------- Fallback: round-3 monolithic kernel ----------------
__global__ __launch_bounds__(256, 4)
void gru_fused(const float* __restrict__ ru, const float* __restrict__ en,
               const float* __restrict__ ruWih, const float* __restrict__ ruWhh,
               const float* __restrict__ rubih, const float* __restrict__ rubhh,
               const float* __restrict__ enWih, const float* __restrict__ enWhh,
               const float* __restrict__ enbih, const float* __restrict__ enbhh,
               const float* __restrict__ W1, const float* __restrict__ b1,
               const float* __restrict__ W2, const float* __restrict__ b2,
               float* __restrict__ out)
{
    const int tid  = threadIdx.x;
    const int wv   = tid >> 6;
    const int lane = tid & 63;
    const int g    = lane & 31;
    const int h    = lane >> 5;
    const int wid  = blockIdx.x * 4 + wv;
    const int gru  = wid >> 11;
    const int b    = wid & (BB - 1);

    const float* __restrict__ x   = gru ? en    : ru;
    const float* __restrict__ Wih = gru ? enWih : ruWih;
    const float* __restrict__ Whh = gru ? enWhh : ruWhh;
    const float* __restrict__ bih = gru ? enbih : rubih;
    const float* __restrict__ bhh = gru ? enbhh : rubhh;

    __shared__ __align__(16) float lds[4][176];
    float* __restrict__ X    = lds[wv];
    float* __restrict__ PRE  = X + 132;
    float* __restrict__ Hbuf = X + 164;

    const int gq = (g < 30) ? g : 0;
    float wih[64];
    #pragma unroll
    for (int j = 0; j < 64; ++j) wih[j] = Wih[gq * II + h * 64 + j];
    const float w_e = Wih[gq * II + 128 + h];
    float whh[10];
    #pragma unroll
    for (int k = 0; k < 10; ++k) whh[k] = Whh[gq * 10 + k];
    const float bihg = bih[gq];
    const float bhhg = bhh[gq];

    if (lane < 12) Hbuf[lane] = 0.f;
    float hown = 0.f;

    const float* __restrict__ xrow = x + (size_t)b * (TT * II);
    float xa = xrow[lane];
    float xb = xrow[64 + lane];
    float xc = (lane < 2) ? xrow[128 + lane] : 0.f;

    for (int t = 0; t < TT; ++t) {
        X[lane] = xa;
        X[64 + lane] = xb;
        if (lane < 2) X[128 + lane] = xc;
        {
            const int tn = (t < TT - 1) ? t + 1 : t;
            const float* __restrict__ xn = xrow + (size_t)tn * II;
            xa = xn[lane];
            xb = xn[64 + lane];
            xc = (lane < 2) ? xn[128 + lane] : 0.f;
        }
        const float4 h03 = *(const float4*)(Hbuf);
        const float4 h47 = *(const float4*)(Hbuf + 4);
        const float2 h89 = *(const float2*)(Hbuf + 8);
        float gh0 = fmaf(whh[0], h03.x, bhhg);
        float gh1 = whh[1] * h03.y;
        gh0 = fmaf(whh[2], h03.z, gh0);
        gh1 = fmaf(whh[3], h03.w, gh1);
        gh0 = fmaf(whh[4], h47.x, gh0);
        gh1 = fmaf(whh[5], h47.y, gh1);
        gh0 = fmaf(whh[6], h47.z, gh0);
        gh1 = fmaf(whh[7], h47.w, gh1);
        gh0 = fmaf(whh[8], h89.x, gh0);
        gh1 = fmaf(whh[9], h89.y, gh1);
        const float gh = gh0 + gh1;

        float s0 = 0.f, s1 = 0.f, s2 = 0.f, s3 = 0.f;
        const float4* __restrict__ xb4 = (const float4*)(X + h * 64);
        #pragma unroll
        for (int c = 0; c < 16; ++c) {
            const float4 v = xb4[c];
            s0 = fmaf(wih[4 * c + 0], v.x, s0);
            s1 = fmaf(wih[4 * c + 1], v.y, s1);
            s2 = fmaf(wih[4 * c + 2], v.z, s2);
            s3 = fmaf(wih[4 * c + 3], v.w, s3);
        }
        float s = (s0 + s1) + (s2 + s3);
        s = fmaf(w_e, X[128 + h], s);
        s += __shfl_xor(s, 32);

        const float xiv = s + bihg;
        const float pre = xiv + gh;
        if (lane < 30) PRE[lane] = pre;
        const float rpre = PRE[(g - 20) & 31];
        const float zpre = PRE[(g - 10) & 31];
        const float r = sigmoidf_fast(rpre);
        const float z = sigmoidf_fast(zpre);
        const float n = tanhf_fast(xiv + r * gh);
        const float hnew = (1.f - z) * n + z * hown;
        hown = hnew;
        if (lane >= 20 && lane < 30) Hbuf[lane - 20] = hnew;
    }

    float val = 0.f;
    if (lane < 10) {
        const float hk = Hbuf[lane];
        float v = 0.f;
        #pragma unroll
        for (int d = 0; d < 20; ++d)
            v = fmaf(W2[d], W1[d * 20 + gru * 10 + lane], v);
        val = v * hk;
        if (lane == 0 && gru == 0) {
            float c0 = b2[0];
            #pragma unroll
            for (int d = 0; d < 20; ++d) c0 = fmaf(W2[d], b1[d], c0);
            val += c0;
        }
    }
    #pragma unroll
    for (int o = 32; o > 0; o >>= 1) val += __shfl_xor(val, o);
    if (lane == 0) atomicAdd(&out[b], val);
}

extern "C" void kernel_launch(void* const* d_in, const int* in_sizes, int n_in,
                              void* d_out, int out_size, void* d_ws, size_t ws_size,
                              hipStream_t stream) {
    (void)in_sizes; (void)n_in;
    const float* ru    = (const float*)d_in[0];
    const float* en    = (const float*)d_in[1];
    const float* ruWih = (const float*)d_in[2];
    const float* ruWhh = (const float*)d_in[3];
    const float* rubih = (const float*)d_in[4];
    const float* rubhh = (const float*)d_in[5];
    const float* enWih = (const float*)d_in[6];
    const float* enWhh = (const float*)d_in[7];
    const float* enbih = (const float*)d_in[8];
    const float* enbhh = (const float*)d_in[9];
    const float* W1    = (const float*)d_in[10];
    const float* b1    = (const float*)d_in[11];
    const float* W2    = (const float*)d_in[12];
    const float* b2    = (const float*)d_in[13];
    float* out = (float*)d_out;

    hipMemsetAsync(d_out, 0, (size_t)out_size * sizeof(float), stream);

    const size_t xi_bytes = (size_t)ROWS_TOTAL * 30 * sizeof(float);  // ~63 MB
    if (ws_size >= xi_bytes) {
        float* xi = (float*)d_ws;
        // Phase 1: 8192 waves, 64 rows each
        xi_gemm<<<dim3(2048), dim3(256), 0, stream>>>(
            ru, en, ruWih, rubih, enWih, enbih, xi);
        // Phase 2: 4096 chains, 2 per wave
        gru_scan<<<dim3(512), dim3(256), 0, stream>>>(
            xi, ruWhh, rubhh, enWhh, enbhh, W1, b1, W2, b2, out);
    } else {
        gru_fused<<<dim3(1024), dim3(256), 0, stream>>>(
            ru, en, ruWih, ruWhh, rubih, rubhh,
            enWih, enWhh, enbih, enbhh, W1, b1, W2, b2, out);
    }
}

// Round 5
// 161.057 us; speedup vs baseline: 1.0174x; 1.0174x over previous
//
#include <hip/hip_runtime.h>

// B=2048, T=128, I=130, H=10, 3H=30, D1=20
// Two-phase design:
//   Phase 1 (xi_gemm): xi[row][g] = Wih[g,:].x_row + bih[g] for all 524288
//     rows. Round-5: __launch_bounds__(256,3) so wih[64] is arch-VGPR
//     resident (round-4 showed VGPR=52 -> AGPR/remat per-fma overhead),
//     2-row unroll (each wih reg feeds 2 fma; 2x independent chains to hide
//     ds_read latency), uniform-branch prefetch, paired divergent store.
//   Phase 2 (gru_scan): serial scan, 2 chains/wave, lane k<10 computes all
//     three gates; one LDS h-roundtrip/step; xi streamed 2-deep (L3-hot).
// Fallback: monolithic kernel if ws_size < 63 MB.

#define BB 2048
#define TT 128
#define II 130
#define ROWS_PER_GRU (BB * TT)          // 262144
#define ROWS_TOTAL   (2 * ROWS_PER_GRU) // 524288

__device__ __forceinline__ float sigmoidf_fast(float x) {
    return __fdividef(1.f, 1.f + __expf(-x));
}
__device__ __forceinline__ float tanhf_fast(float x) {
    float ax = fabsf(x);
    float e = __expf(-2.f * ax);
    float t = __fdividef(1.f - e, 1.f + e);
    return copysignf(t, x);
}

// ---------------- Phase 1: input projection GEMM ----------------
__global__ __launch_bounds__(256, 3)
void xi_gemm(const float* __restrict__ ru, const float* __restrict__ en,
             const float* __restrict__ ruWih, const float* __restrict__ rubih,
             const float* __restrict__ enWih, const float* __restrict__ enbih,
             float* __restrict__ xi)
{
    const int tid  = threadIdx.x;
    const int wv   = tid >> 6;
    const int lane = tid & 63;
    const int g    = lane & 31;        // gate 0..29 active
    const int h    = lane >> 5;        // K-half
    const int w    = blockIdx.x * 4 + wv;       // wave id 0..8191
    const int gru  = (w >= 4096);
    const long row0 = (long)w * 64;             // 64 rows per wave

    const float* __restrict__ x   = gru ? en    : ru;
    const float* __restrict__ Wih = gru ? enWih : ruWih;
    const float* __restrict__ bih = gru ? enbih : rubih;

    const int gq = (g < 30) ? g : 0;
    float wih[64];
    #pragma unroll
    for (int j = 0; j < 64; ++j) wih[j] = Wih[gq * II + h * 64 + j];
    const float w_e  = Wih[gq * II + 128 + h];
    const float bihg = bih[gq];

    __shared__ __align__(16) float lds[4][2][132];
    float* __restrict__ X0 = lds[wv][0];
    float* __restrict__ X1 = lds[wv][1];

    const long r0l = row0 - (long)gru * ROWS_PER_GRU;
    const float* __restrict__ xrow = x + r0l * II;
    float* __restrict__ xo = xi + row0 * 30;

    // prefetch rows 0,1
    float a0 = xrow[lane],      a1 = xrow[64 + lane];
    float a2 = (lane < 2) ? xrow[128 + lane] : 0.f;
    float b0 = xrow[II + lane], b1 = xrow[II + 64 + lane];
    float b2 = (lane < 2) ? xrow[II + 128 + lane] : 0.f;

    for (int i = 0; i < 64; i += 2) {
        // stage both rows (in-wave DS ordering is FIFO; no barrier)
        X0[lane] = a0; X0[64 + lane] = a1; if (lane < 2) X0[128 + lane] = a2;
        X1[lane] = b0; X1[64 + lane] = b1; if (lane < 2) X1[128 + lane] = b2;

        if (i < 62) {   // uniform branch: prefetch rows i+2, i+3
            const float* __restrict__ q0 = xrow + (long)(i + 2) * II;
            const float* __restrict__ q1 = xrow + (long)(i + 3) * II;
            a0 = q0[lane]; a1 = q0[64 + lane];
            a2 = (lane < 2) ? q0[128 + lane] : 0.f;
            b0 = q1[lane]; b1 = q1[64 + lane];
            b2 = (lane < 2) ? q1[128 + lane] : 0.f;
        }

        // two rows' half-dots, interleaved (each wih reg feeds 2 fma)
        float s0 = 0.f, s1 = 0.f, s2 = 0.f, s3 = 0.f;
        float u0 = 0.f, u1 = 0.f, u2 = 0.f, u3 = 0.f;
        const float4* __restrict__ xa4 = (const float4*)(X0 + h * 64);
        const float4* __restrict__ xb4 = (const float4*)(X1 + h * 64);
        #pragma unroll
        for (int c = 0; c < 16; ++c) {
            const float4 va = xa4[c];
            const float4 vb = xb4[c];
            s0 = fmaf(wih[4 * c + 0], va.x, s0); u0 = fmaf(wih[4 * c + 0], vb.x, u0);
            s1 = fmaf(wih[4 * c + 1], va.y, s1); u1 = fmaf(wih[4 * c + 1], vb.y, u1);
            s2 = fmaf(wih[4 * c + 2], va.z, s2); u2 = fmaf(wih[4 * c + 2], vb.z, u2);
            s3 = fmaf(wih[4 * c + 3], va.w, s3); u3 = fmaf(wih[4 * c + 3], vb.w, u3);
        }
        float s = (s0 + s1) + (s2 + s3);
        float u = (u0 + u1) + (u2 + u3);
        s = fmaf(w_e, X0[128 + h], s);
        u = fmaf(w_e, X1[128 + h], u);
        s += __shfl_xor(s, 32);          // combine K-halves
        u += __shfl_xor(u, 32);

        // paired store: row i from h=0 lanes, row i+1 from h=1 lanes
        if (g < 30) {
            const long ro = h ? (long)(i + 1) * 30 : (long)i * 30;
            const float vo = h ? (u + bihg) : (s + bihg);
            xo[ro + g] = vo;
        }
    }
}

// ---------------- Phase 2: recurrent scan ----------------
__global__ __launch_bounds__(256, 4)
void gru_scan(const float* __restrict__ xi,
              const float* __restrict__ ruWhh, const float* __restrict__ rubhh,
              const float* __restrict__ enWhh, const float* __restrict__ enbhh,
              const float* __restrict__ W1, const float* __restrict__ b1,
              const float* __restrict__ W2, const float* __restrict__ b2,
              float* __restrict__ out)
{
    const int tid  = threadIdx.x;
    const int wv   = tid >> 6;
    const int lane = tid & 63;
    const int c    = lane >> 5;        // chain slot in wave (0/1)
    const int k    = lane & 31;        // hidden index, 0..9 active
    const int kq   = (k < 10) ? k : 0;
    const int chain = (blockIdx.x * 4 + wv) * 2 + c;   // 0..4095
    const int gru   = chain >> 11;
    const int b     = chain & (BB - 1);

    const float* __restrict__ Whh = gru ? enWhh : ruWhh;
    const float* __restrict__ bhh = gru ? enbhh : rubhh;

    float whhR[10], whhZ[10], whhN[10];
    #pragma unroll
    for (int j = 0; j < 10; ++j) {
        whhR[j] = Whh[kq * 10 + j];
        whhZ[j] = Whh[(10 + kq) * 10 + j];
        whhN[j] = Whh[(20 + kq) * 10 + j];
    }
    const float bR = bhh[kq], bZ = bhh[10 + kq], bN = bhh[20 + kq];

    __shared__ __align__(16) float lds[4][32];
    float* __restrict__ H = lds[wv] + c * 16;
    if (k < 12) H[k] = 0.f;
    float hown = 0.f;

    const float* __restrict__ xrow =
        xi + ((long)gru * ROWS_PER_GRU + (long)b * TT) * 30;

    float xR0 = xrow[kq],      xZ0 = xrow[10 + kq],  xN0 = xrow[20 + kq];
    float xR1 = xrow[30 + kq], xZ1 = xrow[40 + kq],  xN1 = xrow[50 + kq];

    for (int t = 0; t < TT; ++t) {
        const float xR = xR0, xZ = xZ0, xN = xN0;
        xR0 = xR1; xZ0 = xZ1; xN0 = xN1;
        {
            const int tn = (t + 2 < TT) ? t + 2 : TT - 1;
            const float* __restrict__ xp = xrow + (long)tn * 30;
            xR1 = xp[kq]; xZ1 = xp[10 + kq]; xN1 = xp[20 + kq];
        }

        const float4 h03 = *(const float4*)(H);
        const float4 h47 = *(const float4*)(H + 4);
        const float2 h89 = *(const float2*)(H + 8);

        float gr = bR, gz = bZ, gn = bN;
        gr = fmaf(whhR[0], h03.x, gr); gz = fmaf(whhZ[0], h03.x, gz); gn = fmaf(whhN[0], h03.x, gn);
        gr = fmaf(whhR[1], h03.y, gr); gz = fmaf(whhZ[1], h03.y, gz); gn = fmaf(whhN[1], h03.y, gn);
        gr = fmaf(whhR[2], h03.z, gr); gz = fmaf(whhZ[2], h03.z, gz); gn = fmaf(whhN[2], h03.z, gn);
        gr = fmaf(whhR[3], h03.w, gr); gz = fmaf(whhZ[3], h03.w, gz); gn = fmaf(whhN[3], h03.w, gn);
        gr = fmaf(whhR[4], h47.x, gr); gz = fmaf(whhZ[4], h47.x, gz); gn = fmaf(whhN[4], h47.x, gn);
        gr = fmaf(whhR[5], h47.y, gr); gz = fmaf(whhZ[5], h47.y, gz); gn = fmaf(whhN[5], h47.y, gn);
        gr = fmaf(whhR[6], h47.z, gr); gz = fmaf(whhZ[6], h47.z, gz); gn = fmaf(whhN[6], h47.z, gn);
        gr = fmaf(whhR[7], h47.w, gr); gz = fmaf(whhZ[7], h47.w, gz); gn = fmaf(whhN[7], h47.w, gn);
        gr = fmaf(whhR[8], h89.x, gr); gz = fmaf(whhZ[8], h89.x, gz); gn = fmaf(whhN[8], h89.x, gn);
        gr = fmaf(whhR[9], h89.y, gr); gz = fmaf(whhZ[9], h89.y, gz); gn = fmaf(whhN[9], h89.y, gn);

        const float r = sigmoidf_fast(xR + gr);
        const float z = sigmoidf_fast(xZ + gz);
        const float n = tanhf_fast(xN + r * gn);
        const float hnew = fmaf(z, hown - n, n);
        hown = hnew;
        if (k < 10) H[k] = hnew;
    }

    float val = 0.f;
    if (k < 10) {
        float v = 0.f;
        #pragma unroll
        for (int d = 0; d < 20; ++d)
            v = fmaf(W2[d], W1[d * 20 + gru * 10 + k], v);
        val = v * hown;
        if (k == 0 && gru == 0) {
            float c0 = b2[0];
            #pragma unroll
            for (int d = 0; d < 20; ++d) c0 = fmaf(W2[d], b1[d], c0);
            val += c0;
        }
    }
    val += __shfl_xor(val, 8);
    val += __shfl_xor(val, 4);
    val += __shfl_xor(val, 2);
    val += __shfl_xor(val, 1);
    if (k == 0) atomicAdd(&out[b], val);
}

// ---------------- Fallback: monolithic kernel ----------------
__global__ __launch_bounds__(256, 4)
void gru_fused(const float* __restrict__ ru, const float* __restrict__ en,
               const float* __restrict__ ruWih, const float* __restrict__ ruWhh,
               const float* __restrict__ rubih, const float* __restrict__ rubhh,
               const float* __restrict__ enWih, const float* __restrict__ enWhh,
               const float* __restrict__ enbih, const float* __restrict__ enbhh,
               const float* __restrict__ W1, const float* __restrict__ b1,
               const float* __restrict__ W2, const float* __restrict__ b2,
               float* __restrict__ out)
{
    const int tid  = threadIdx.x;
    const int wv   = tid >> 6;
    const int lane = tid & 63;
    const int g    = lane & 31;
    const int h    = lane >> 5;
    const int wid  = blockIdx.x * 4 + wv;
    const int gru  = wid >> 11;
    const int b    = wid & (BB - 1);

    const float* __restrict__ x   = gru ? en    : ru;
    const float* __restrict__ Wih = gru ? enWih : ruWih;
    const float* __restrict__ Whh = gru ? enWhh : ruWhh;
    const float* __restrict__ bih = gru ? enbih : rubih;
    const float* __restrict__ bhh = gru ? enbhh : rubhh;

    __shared__ __align__(16) float lds[4][176];
    float* __restrict__ X    = lds[wv];
    float* __restrict__ PRE  = X + 132;
    float* __restrict__ Hbuf = X + 164;

    const int gq = (g < 30) ? g : 0;
    float wih[64];
    #pragma unroll
    for (int j = 0; j < 64; ++j) wih[j] = Wih[gq * II + h * 64 + j];
    const float w_e = Wih[gq * II + 128 + h];
    float whh[10];
    #pragma unroll
    for (int k = 0; k < 10; ++k) whh[k] = Whh[gq * 10 + k];
    const float bihg = bih[gq];
    const float bhhg = bhh[gq];

    if (lane < 12) Hbuf[lane] = 0.f;
    float hown = 0.f;

    const float* __restrict__ xrow = x + (size_t)b * (TT * II);
    float xa = xrow[lane];
    float xb = xrow[64 + lane];
    float xc = (lane < 2) ? xrow[128 + lane] : 0.f;

    for (int t = 0; t < TT; ++t) {
        X[lane] = xa;
        X[64 + lane] = xb;
        if (lane < 2) X[128 + lane] = xc;
        {
            const int tn = (t < TT - 1) ? t + 1 : t;
            const float* __restrict__ xn = xrow + (size_t)tn * II;
            xa = xn[lane];
            xb = xn[64 + lane];
            xc = (lane < 2) ? xn[128 + lane] : 0.f;
        }
        const float4 h03 = *(const float4*)(Hbuf);
        const float4 h47 = *(const float4*)(Hbuf + 4);
        const float2 h89 = *(const float2*)(Hbuf + 8);
        float gh0 = fmaf(whh[0], h03.x, bhhg);
        float gh1 = whh[1] * h03.y;
        gh0 = fmaf(whh[2], h03.z, gh0);
        gh1 = fmaf(whh[3], h03.w, gh1);
        gh0 = fmaf(whh[4], h47.x, gh0);
        gh1 = fmaf(whh[5], h47.y, gh1);
        gh0 = fmaf(whh[6], h47.z, gh0);
        gh1 = fmaf(whh[7], h47.w, gh1);
        gh0 = fmaf(whh[8], h89.x, gh0);
        gh1 = fmaf(whh[9], h89.y, gh1);
        const float gh = gh0 + gh1;

        float s0 = 0.f, s1 = 0.f, s2 = 0.f, s3 = 0.f;
        const float4* __restrict__ xb4 = (const float4*)(X + h * 64);
        #pragma unroll
        for (int c = 0; c < 16; ++c) {
            const float4 v = xb4[c];
            s0 = fmaf(wih[4 * c + 0], v.x, s0);
            s1 = fmaf(wih[4 * c + 1], v.y, s1);
            s2 = fmaf(wih[4 * c + 2], v.z, s2);
            s3 = fmaf(wih[4 * c + 3], v.w, s3);
        }
        float s = (s0 + s1) + (s2 + s3);
        s = fmaf(w_e, X[128 + h], s);
        s += __shfl_xor(s, 32);

        const float xiv = s + bihg;
        const float pre = xiv + gh;
        if (lane < 30) PRE[lane] = pre;
        const float rpre = PRE[(g - 20) & 31];
        const float zpre = PRE[(g - 10) & 31];
        const float r = sigmoidf_fast(rpre);
        const float z = sigmoidf_fast(zpre);
        const float n = tanhf_fast(xiv + r * gh);
        const float hnew = (1.f - z) * n + z * hown;
        hown = hnew;
        if (lane >= 20 && lane < 30) Hbuf[lane - 20] = hnew;
    }

    float val = 0.f;
    if (lane < 10) {
        const float hk = Hbuf[lane];
        float v = 0.f;
        #pragma unroll
        for (int d = 0; d < 20; ++d)
            v = fmaf(W2[d], W1[d * 20 + gru * 10 + lane], v);
        val = v * hk;
        if (lane == 0 && gru == 0) {
            float c0 = b2[0];
            #pragma unroll
            for (int d = 0; d < 20; ++d) c0 = fmaf(W2[d], b1[d], c0);
            val += c0;
        }
    }
    #pragma unroll
    for (int o = 32; o > 0; o >>= 1) val += __shfl_xor(val, o);
    if (lane == 0) atomicAdd(&out[b], val);
}

extern "C" void kernel_launch(void* const* d_in, const int* in_sizes, int n_in,
                              void* d_out, int out_size, void* d_ws, size_t ws_size,
                              hipStream_t stream) {
    (void)in_sizes; (void)n_in;
    const float* ru    = (const float*)d_in[0];
    const float* en    = (const float*)d_in[1];
    const float* ruWih = (const float*)d_in[2];
    const float* ruWhh = (const float*)d_in[3];
    const float* rubih = (const float*)d_in[4];
    const float* rubhh = (const float*)d_in[5];
    const float* enWih = (const float*)d_in[6];
    const float* enWhh = (const float*)d_in[7];
    const float* enbih = (const float*)d_in[8];
    const float* enbhh = (const float*)d_in[9];
    const float* W1    = (const float*)d_in[10];
    const float* b1    = (const float*)d_in[11];
    const float* W2    = (const float*)d_in[12];
    const float* b2    = (const float*)d_in[13];
    float* out = (float*)d_out;

    hipMemsetAsync(d_out, 0, (size_t)out_size * sizeof(float), stream);

    const size_t xi_bytes = (size_t)ROWS_TOTAL * 30 * sizeof(float);  // ~63 MB
    if (ws_size >= xi_bytes) {
        float* xi = (float*)d_ws;
        xi_gemm<<<dim3(2048), dim3(256), 0, stream>>>(
            ru, en, ruWih, rubih, enWih, enbih, xi);
        gru_scan<<<dim3(512), dim3(256), 0, stream>>>(
            xi, ruWhh, rubhh, enWhh, enbhh, W1, b1, W2, b2, out);
    } else {
        gru_fused<<<dim3(1024), dim3(256), 0, stream>>>(
            ru, en, ruWih, ruWhh, rubih, rubhh,
            enWih, enWhh, enbih, enbhh, W1, b1, W2, b2, out);
    }
}

// Round 6
// 142.058 us; speedup vs baseline: 1.1534x; 1.1337x over previous
//
#include <hip/hip_runtime.h>
#include <hip/hip_bf16.h>

// B=2048, T=128, I=130, H=10, 3H=30, D1=20
// Phase 1 (xi_gemm, MFMA): xi = x @ Wih^T + bih over 524288 rows.
//   fp32 emulated as bf16 hi/lo split (3 mfma terms: hi*hi + hi*lo + lo*hi,
//   residual ~2^-16 rel). mfma_f32_16x16x32_bf16, fp32 accumulate.
//   Per wave: 64 rows (4 M-tiles) x K=128 (4 k-blocks) x N=32 (2 n-tiles,
//   cols 30,31 masked). k=128,129 tail + bias folded in via VALU on the
//   C fragments. No LDS anywhere (round-5 counters: LDS pipe + write->read
//   ordering was ~half the per-row cost; VALU multiply work is the other ->
//   both eliminated/moved to matrix pipe).
// Phase 2 (gru_scan): unchanged from round 5.
// Fallback: monolithic kernel if ws_size < 63 MB.

#define BB 2048
#define TT 128
#define II 130
#define ROWS_PER_GRU (BB * TT)          // 262144
#define ROWS_TOTAL   (2 * ROWS_PER_GRU) // 524288

typedef __attribute__((ext_vector_type(8))) short short8v;  // 8 bf16
typedef __attribute__((ext_vector_type(4))) float f32x4;

__device__ __forceinline__ float sigmoidf_fast(float x) {
    return __fdividef(1.f, 1.f + __expf(-x));
}
__device__ __forceinline__ float tanhf_fast(float x) {
    float ax = fabsf(x);
    float e = __expf(-2.f * ax);
    float t = __fdividef(1.f - e, 1.f + e);
    return copysignf(t, x);
}

// truncation split of 2 fp32 -> packed bf16-hi pair + bf16-lo pair
__device__ __forceinline__ void split2(float x0, float x1,
                                       unsigned& hi, unsigned& lo) {
    unsigned u0 = __float_as_uint(x0), u1 = __float_as_uint(x1);
    hi = (u0 >> 16) | (u1 & 0xffff0000u);
    float f0 = __uint_as_float(u0 & 0xffff0000u);
    float f1 = __uint_as_float(u1 & 0xffff0000u);
    unsigned l0 = __float_as_uint(x0 - f0);
    unsigned l1 = __float_as_uint(x1 - f1);
    lo = (l0 >> 16) | (l1 & 0xffff0000u);
}

union U8 { unsigned u[4]; short8v v; };

// load 8 consecutive fp32 (8B-aligned) and split into bf16x8 hi/lo frags
__device__ __forceinline__ void load_split(const float* __restrict__ p,
                                           short8v& hi, short8v& lo) {
    U8 H, L;
    #pragma unroll
    for (int i = 0; i < 4; ++i) {
        const float2 xy = *(const float2*)(p + 2 * i);
        split2(xy.x, xy.y, H.u[i], L.u[i]);
    }
    hi = H.v; lo = L.v;
}

// ---------------- Phase 1: input projection via MFMA ----------------
__global__ __launch_bounds__(256)
void xi_gemm(const float* __restrict__ ru, const float* __restrict__ en,
             const float* __restrict__ ruWih, const float* __restrict__ rubih,
             const float* __restrict__ enWih, const float* __restrict__ enbih,
             float* __restrict__ xi)
{
    const int tid  = threadIdx.x;
    const int lane = tid & 63;
    const int lr   = lane & 15;          // A-row / B-col / C-col slot
    const int lk   = lane >> 4;          // k-subblock (0..3)
    const int w    = blockIdx.x * 4 + (tid >> 6);   // wave 0..8191
    const int gru  = (w >= 4096);
    const long row0 = (long)(w & 4095) * 64;        // local row in this gru

    const float* __restrict__ X   = gru ? en    : ru;
    const float* __restrict__ Wf  = gru ? enWih : ruWih;
    const float* __restrict__ bih = gru ? enbih : rubih;

    // ---- B fragments (weights), hi/lo, 2 n-tiles x 4 k-blocks ----
    short8v Bhi[2][4], Blo[2][4];
    float biasv[2], wt0[2], wt1[2];
    #pragma unroll
    for (int t = 0; t < 2; ++t) {
        const int g = 16 * t + lr;
        const int gv = (g < 30) ? g : 0;
        #pragma unroll
        for (int q = 0; q < 4; ++q)
            load_split(Wf + (long)gv * II + 32 * q + 8 * lk, Bhi[t][q], Blo[t][q]);
        if (g >= 30) {                    // mask cols 30,31
            const short8v z = {0, 0, 0, 0, 0, 0, 0, 0};
            #pragma unroll
            for (int q = 0; q < 4; ++q) { Bhi[t][q] = z; Blo[t][q] = z; }
        }
        biasv[t] = bih[gv];
        const float2 wt = *(const float2*)(Wf + (long)gv * II + 128);
        wt0[t] = wt.x; wt1[t] = wt.y;
    }

    // ---- C accumulators: 4 M-tiles x 2 n-tiles, init = bias ----
    f32x4 acc[4][2];
    #pragma unroll
    for (int m = 0; m < 4; ++m)
        #pragma unroll
        for (int t = 0; t < 2; ++t)
            acc[m][t] = (f32x4){biasv[t], biasv[t], biasv[t], biasv[t]};

    // ---- main: A frags straight from global, 3 mfma per (m,q,t) ----
    #pragma unroll
    for (int m = 0; m < 4; ++m) {
        const float* __restrict__ xr = X + (row0 + 16 * m + lr) * (long)II;
        #pragma unroll
        for (int q = 0; q < 4; ++q) {
            short8v ahi, alo;
            load_split(xr + 32 * q + 8 * lk, ahi, alo);
            acc[m][0] = __builtin_amdgcn_mfma_f32_16x16x32_bf16(ahi, Bhi[0][q], acc[m][0], 0, 0, 0);
            acc[m][0] = __builtin_amdgcn_mfma_f32_16x16x32_bf16(ahi, Blo[0][q], acc[m][0], 0, 0, 0);
            acc[m][0] = __builtin_amdgcn_mfma_f32_16x16x32_bf16(alo, Bhi[0][q], acc[m][0], 0, 0, 0);
            acc[m][1] = __builtin_amdgcn_mfma_f32_16x16x32_bf16(ahi, Bhi[1][q], acc[m][1], 0, 0, 0);
            acc[m][1] = __builtin_amdgcn_mfma_f32_16x16x32_bf16(ahi, Blo[1][q], acc[m][1], 0, 0, 0);
            acc[m][1] = __builtin_amdgcn_mfma_f32_16x16x32_bf16(alo, Bhi[1][q], acc[m][1], 0, 0, 0);
        }
    }

    // ---- k-tail (128,129) + store. C layout: row=(lane>>4)*4+r, col=lane&15 ----
    const long gb = (long)gru * ROWS_PER_GRU;
    #pragma unroll
    for (int m = 0; m < 4; ++m) {
        #pragma unroll
        for (int r = 0; r < 4; ++r) {
            const long rr = row0 + 16 * m + 4 * lk + r;
            const float2 xt = *(const float2*)(X + rr * (long)II + 128);
            float* __restrict__ xo = xi + (gb + rr) * 30;
            const float v0 = acc[m][0][r] + xt.x * wt0[0] + xt.y * wt1[0];
            xo[lr] = v0;                              // t=0: g=lr (0..15), valid
            if (lr < 14) {
                const float v1 = acc[m][1][r] + xt.x * wt0[1] + xt.y * wt1[1];
                xo[16 + lr] = v1;                     // t=1: g=16+lr (16..29)
            }
        }
    }
}

// ---------------- Phase 2: recurrent scan (unchanged) ----------------
__global__ __launch_bounds__(256, 4)
void gru_scan(const float* __restrict__ xi,
              const float* __restrict__ ruWhh, const float* __restrict__ rubhh,
              const float* __restrict__ enWhh, const float* __restrict__ enbhh,
              const float* __restrict__ W1, const float* __restrict__ b1,
              const float* __restrict__ W2, const float* __restrict__ b2,
              float* __restrict__ out)
{
    const int tid  = threadIdx.x;
    const int wv   = tid >> 6;
    const int lane = tid & 63;
    const int c    = lane >> 5;
    const int k    = lane & 31;
    const int kq   = (k < 10) ? k : 0;
    const int chain = (blockIdx.x * 4 + wv) * 2 + c;
    const int gru   = chain >> 11;
    const int b     = chain & (BB - 1);

    const float* __restrict__ Whh = gru ? enWhh : ruWhh;
    const float* __restrict__ bhh = gru ? enbhh : rubhh;

    float whhR[10], whhZ[10], whhN[10];
    #pragma unroll
    for (int j = 0; j < 10; ++j) {
        whhR[j] = Whh[kq * 10 + j];
        whhZ[j] = Whh[(10 + kq) * 10 + j];
        whhN[j] = Whh[(20 + kq) * 10 + j];
    }
    const float bR = bhh[kq], bZ = bhh[10 + kq], bN = bhh[20 + kq];

    __shared__ __align__(16) float lds[4][32];
    float* __restrict__ H = lds[wv] + c * 16;
    if (k < 12) H[k] = 0.f;
    float hown = 0.f;

    const float* __restrict__ xrow =
        xi + ((long)gru * ROWS_PER_GRU + (long)b * TT) * 30;

    float xR0 = xrow[kq],      xZ0 = xrow[10 + kq],  xN0 = xrow[20 + kq];
    float xR1 = xrow[30 + kq], xZ1 = xrow[40 + kq],  xN1 = xrow[50 + kq];

    for (int t = 0; t < TT; ++t) {
        const float xR = xR0, xZ = xZ0, xN = xN0;
        xR0 = xR1; xZ0 = xZ1; xN0 = xN1;
        {
            const int tn = (t + 2 < TT) ? t + 2 : TT - 1;
            const float* __restrict__ xp = xrow + (long)tn * 30;
            xR1 = xp[kq]; xZ1 = xp[10 + kq]; xN1 = xp[20 + kq];
        }

        const float4 h03 = *(const float4*)(H);
        const float4 h47 = *(const float4*)(H + 4);
        const float2 h89 = *(const float2*)(H + 8);

        float gr = bR, gz = bZ, gn = bN;
        gr = fmaf(whhR[0], h03.x, gr); gz = fmaf(whhZ[0], h03.x, gz); gn = fmaf(whhN[0], h03.x, gn);
        gr = fmaf(whhR[1], h03.y, gr); gz = fmaf(whhZ[1], h03.y, gz); gn = fmaf(whhN[1], h03.y, gn);
        gr = fmaf(whhR[2], h03.z, gr); gz = fmaf(whhZ[2], h03.z, gz); gn = fmaf(whhN[2], h03.z, gn);
        gr = fmaf(whhR[3], h03.w, gr); gz = fmaf(whhZ[3], h03.w, gz); gn = fmaf(whhN[3], h03.w, gn);
        gr = fmaf(whhR[4], h47.x, gr); gz = fmaf(whhZ[4], h47.x, gz); gn = fmaf(whhN[4], h47.x, gn);
        gr = fmaf(whhR[5], h47.y, gr); gz = fmaf(whhZ[5], h47.y, gz); gn = fmaf(whhN[5], h47.y, gn);
        gr = fmaf(whhR[6], h47.z, gr); gz = fmaf(whhZ[6], h47.z, gz); gn = fmaf(whhN[6], h47.z, gn);
        gr = fmaf(whhR[7], h47.w, gr); gz = fmaf(whhZ[7], h47.w, gz); gn = fmaf(whhN[7], h47.w, gn);
        gr = fmaf(whhR[8], h89.x, gr); gz = fmaf(whhZ[8], h89.x, gz); gn = fmaf(whhN[8], h89.x, gn);
        gr = fmaf(whhR[9], h89.y, gr); gz = fmaf(whhZ[9], h89.y, gz); gn = fmaf(whhN[9], h89.y, gn);

        const float r = sigmoidf_fast(xR + gr);
        const float z = sigmoidf_fast(xZ + gz);
        const float n = tanhf_fast(xN + r * gn);
        const float hnew = fmaf(z, hown - n, n);
        hown = hnew;
        if (k < 10) H[k] = hnew;
    }

    float val = 0.f;
    if (k < 10) {
        float v = 0.f;
        #pragma unroll
        for (int d = 0; d < 20; ++d)
            v = fmaf(W2[d], W1[d * 20 + gru * 10 + k], v);
        val = v * hown;
        if (k == 0 && gru == 0) {
            float c0 = b2[0];
            #pragma unroll
            for (int d = 0; d < 20; ++d) c0 = fmaf(W2[d], b1[d], c0);
            val += c0;
        }
    }
    val += __shfl_xor(val, 8);
    val += __shfl_xor(val, 4);
    val += __shfl_xor(val, 2);
    val += __shfl_xor(val, 1);
    if (k == 0) atomicAdd(&out[b], val);
}

// ---------------- Fallback: monolithic kernel ----------------
__global__ __launch_bounds__(256, 4)
void gru_fused(const float* __restrict__ ru, const float* __restrict__ en,
               const float* __restrict__ ruWih, const float* __restrict__ ruWhh,
               const float* __restrict__ rubih, const float* __restrict__ rubhh,
               const float* __restrict__ enWih, const float* __restrict__ enWhh,
               const float* __restrict__ enbih, const float* __restrict__ enbhh,
               const float* __restrict__ W1, const float* __restrict__ b1,
               const float* __restrict__ W2, const float* __restrict__ b2,
               float* __restrict__ out)
{
    const int tid  = threadIdx.x;
    const int wv   = tid >> 6;
    const int lane = tid & 63;
    const int g    = lane & 31;
    const int h    = lane >> 5;
    const int wid  = blockIdx.x * 4 + wv;
    const int gru  = wid >> 11;
    const int b    = wid & (BB - 1);

    const float* __restrict__ x   = gru ? en    : ru;
    const float* __restrict__ Wih = gru ? enWih : ruWih;
    const float* __restrict__ Whh = gru ? enWhh : ruWhh;
    const float* __restrict__ bih = gru ? enbih : rubih;
    const float* __restrict__ bhh = gru ? enbhh : rubhh;

    __shared__ __align__(16) float lds[4][176];
    float* __restrict__ X    = lds[wv];
    float* __restrict__ PRE  = X + 132;
    float* __restrict__ Hbuf = X + 164;

    const int gq = (g < 30) ? g : 0;
    float wih[64];
    #pragma unroll
    for (int j = 0; j < 64; ++j) wih[j] = Wih[gq * II + h * 64 + j];
    const float w_e = Wih[gq * II + 128 + h];
    float whh[10];
    #pragma unroll
    for (int k = 0; k < 10; ++k) whh[k] = Whh[gq * 10 + k];
    const float bihg = bih[gq];
    const float bhhg = bhh[gq];

    if (lane < 12) Hbuf[lane] = 0.f;
    float hown = 0.f;

    const float* __restrict__ xrow = x + (size_t)b * (TT * II);
    float xa = xrow[lane];
    float xb = xrow[64 + lane];
    float xc = (lane < 2) ? xrow[128 + lane] : 0.f;

    for (int t = 0; t < TT; ++t) {
        X[lane] = xa;
        X[64 + lane] = xb;
        if (lane < 2) X[128 + lane] = xc;
        {
            const int tn = (t < TT - 1) ? t + 1 : t;
            const float* __restrict__ xn = xrow + (size_t)tn * II;
            xa = xn[lane];
            xb = xn[64 + lane];
            xc = (lane < 2) ? xn[128 + lane] : 0.f;
        }
        const float4 h03 = *(const float4*)(Hbuf);
        const float4 h47 = *(const float4*)(Hbuf + 4);
        const float2 h89 = *(const float2*)(Hbuf + 8);
        float gh0 = fmaf(whh[0], h03.x, bhhg);
        float gh1 = whh[1] * h03.y;
        gh0 = fmaf(whh[2], h03.z, gh0);
        gh1 = fmaf(whh[3], h03.w, gh1);
        gh0 = fmaf(whh[4], h47.x, gh0);
        gh1 = fmaf(whh[5], h47.y, gh1);
        gh0 = fmaf(whh[6], h47.z, gh0);
        gh1 = fmaf(whh[7], h47.w, gh1);
        gh0 = fmaf(whh[8], h89.x, gh0);
        gh1 = fmaf(whh[9], h89.y, gh1);
        const float gh = gh0 + gh1;

        float s0 = 0.f, s1 = 0.f, s2 = 0.f, s3 = 0.f;
        const float4* __restrict__ xb4 = (const float4*)(X + h * 64);
        #pragma unroll
        for (int c = 0; c < 16; ++c) {
            const float4 v = xb4[c];
            s0 = fmaf(wih[4 * c + 0], v.x, s0);
            s1 = fmaf(wih[4 * c + 1], v.y, s1);
            s2 = fmaf(wih[4 * c + 2], v.z, s2);
            s3 = fmaf(wih[4 * c + 3], v.w, s3);
        }
        float s = (s0 + s1) + (s2 + s3);
        s = fmaf(w_e, X[128 + h], s);
        s += __shfl_xor(s, 32);

        const float xiv = s + bihg;
        const float pre = xiv + gh;
        if (lane < 30) PRE[lane] = pre;
        const float rpre = PRE[(g - 20) & 31];
        const float zpre = PRE[(g - 10) & 31];
        const float r = sigmoidf_fast(rpre);
        const float z = sigmoidf_fast(zpre);
        const float n = tanhf_fast(xiv + r * gh);
        const float hnew = (1.f - z) * n + z * hown;
        hown = hnew;
        if (lane >= 20 && lane < 30) Hbuf[lane - 20] = hnew;
    }

    float val = 0.f;
    if (lane < 10) {
        const float hk = Hbuf[lane];
        float v = 0.f;
        #pragma unroll
        for (int d = 0; d < 20; ++d)
            v = fmaf(W2[d], W1[d * 20 + gru * 10 + lane], v);
        val = v * hk;
        if (lane == 0 && gru == 0) {
            float c0 = b2[0];
            #pragma unroll
            for (int d = 0; d < 20; ++d) c0 = fmaf(W2[d], b1[d], c0);
            val += c0;
        }
    }
    #pragma unroll
    for (int o = 32; o > 0; o >>= 1) val += __shfl_xor(val, o);
    if (lane == 0) atomicAdd(&out[b], val);
}

extern "C" void kernel_launch(void* const* d_in, const int* in_sizes, int n_in,
                              void* d_out, int out_size, void* d_ws, size_t ws_size,
                              hipStream_t stream) {
    (void)in_sizes; (void)n_in;
    const float* ru    = (const float*)d_in[0];
    const float* en    = (const float*)d_in[1];
    const float* ruWih = (const float*)d_in[2];
    const float* ruWhh = (const float*)d_in[3];
    const float* rubih = (const float*)d_in[4];
    const float* rubhh = (const float*)d_in[5];
    const float* enWih = (const float*)d_in[6];
    const float* enWhh = (const float*)d_in[7];
    const float* enbih = (const float*)d_in[8];
    const float* enbhh = (const float*)d_in[9];
    const float* W1    = (const float*)d_in[10];
    const float* b1    = (const float*)d_in[11];
    const float* W2    = (const float*)d_in[12];
    const float* b2    = (const float*)d_in[13];
    float* out = (float*)d_out;

    hipMemsetAsync(d_out, 0, (size_t)out_size * sizeof(float), stream);

    const size_t xi_bytes = (size_t)ROWS_TOTAL * 30 * sizeof(float);  // ~63 MB
    if (ws_size >= xi_bytes) {
        float* xi = (float*)d_ws;
        xi_gemm<<<dim3(2048), dim3(256), 0, stream>>>(
            ru, en, ruWih, rubih, enWih, enbih, xi);
        gru_scan<<<dim3(512), dim3(256), 0, stream>>>(
            xi, ruWhh, rubhh, enWhh, enbhh, W1, b1, W2, b2, out);
    } else {
        gru_fused<<<dim3(1024), dim3(256), 0, stream>>>(
            ru, en, ruWih, ruWhh, rubih, rubhh,
            enWih, enWhh, enbih, enbhh, W1, b1, W2, b2, out);
    }
}

// Round 7
// 118.575 us; speedup vs baseline: 1.3819x; 1.1980x over previous
//
#include <hip/hip_runtime.h>
#include <hip/hip_bf16.h>

// B=2048, T=128, I=130, H=10, 3H=30, D1=20
// Phase 1 (xi_gemm, MFMA + coalesced staging): xi = x @ Wih^T + bih.
//   Round-7 change: A is streamed via fully-coalesced float4 wave-loads
//   (each wave's 64-row block = contiguous 2080 float4) into a per-wave LDS
//   tile (16 rows), prefetching the next tile into registers during compute.
//   Rounds 4-6 all plateaued at ~135us with per-lane scattered dwordx2 reads
//   (~1 TB/s effective); irreducible-traffic floor is ~53us.
//   MFMA pipeline (bf16 hi/lo split, 3 terms) identical to round 6 (passed,
//   absmax 2e-3). K-tail (cols 128,129) read from the LDS tile.
// Phase 2 (gru_scan): unchanged.
// Fallback: monolithic kernel if ws_size < 63 MB.

#define BB 2048
#define TT 128
#define II 130
#define ROWS_PER_GRU (BB * TT)          // 262144
#define ROWS_TOTAL   (2 * ROWS_PER_GRU) // 524288

typedef __attribute__((ext_vector_type(8))) short short8v;  // 8 bf16
typedef __attribute__((ext_vector_type(4))) float f32x4;

__device__ __forceinline__ float sigmoidf_fast(float x) {
    return __fdividef(1.f, 1.f + __expf(-x));
}
__device__ __forceinline__ float tanhf_fast(float x) {
    float ax = fabsf(x);
    float e = __expf(-2.f * ax);
    float t = __fdividef(1.f - e, 1.f + e);
    return copysignf(t, x);
}

// truncation split of 2 fp32 -> packed bf16-hi pair + bf16-lo pair
__device__ __forceinline__ void split2(float x0, float x1,
                                       unsigned& hi, unsigned& lo) {
    unsigned u0 = __float_as_uint(x0), u1 = __float_as_uint(x1);
    hi = (u0 >> 16) | (u1 & 0xffff0000u);
    float f0 = __uint_as_float(u0 & 0xffff0000u);
    float f1 = __uint_as_float(u1 & 0xffff0000u);
    unsigned l0 = __float_as_uint(x0 - f0);
    unsigned l1 = __float_as_uint(x1 - f1);
    lo = (l0 >> 16) | (l1 & 0xffff0000u);
}

union U8 { unsigned u[4]; short8v v; };

// split 8 consecutive fp32 (8B-aligned, any addrspace) into bf16x8 hi/lo
__device__ __forceinline__ void load_split(const float* __restrict__ p,
                                           short8v& hi, short8v& lo) {
    U8 H, L;
    #pragma unroll
    for (int i = 0; i < 4; ++i) {
        const float2 xy = *(const float2*)(p + 2 * i);
        split2(xy.x, xy.y, H.u[i], L.u[i]);
    }
    hi = H.v; lo = L.v;
}

// ---------------- Phase 1: input projection via MFMA ----------------
__global__ __launch_bounds__(256)
void xi_gemm(const float* __restrict__ ru, const float* __restrict__ en,
             const float* __restrict__ ruWih, const float* __restrict__ rubih,
             const float* __restrict__ enWih, const float* __restrict__ enbih,
             float* __restrict__ xi)
{
    const int tid  = threadIdx.x;
    const int wv   = tid >> 6;
    const int lane = tid & 63;
    const int lr   = lane & 15;          // A-row / B-col / C-col slot
    const int lk   = lane >> 4;          // k-subblock (0..3)
    const int w    = blockIdx.x * 4 + wv;           // wave 0..8191
    const int gru  = (w >= 4096);
    const long row0 = (long)(w & 4095) * 64;        // local row in this gru

    const float* __restrict__ X   = gru ? en    : ru;
    const float* __restrict__ Wf  = gru ? enWih : ruWih;
    const float* __restrict__ bih = gru ? enbih : rubih;

    // ---- B fragments (weights), hi/lo, 2 n-tiles x 4 k-blocks ----
    short8v Bhi[2][4], Blo[2][4];
    float biasv[2], wt0[2], wt1[2];
    #pragma unroll
    for (int t = 0; t < 2; ++t) {
        const int g = 16 * t + lr;
        const int gv = (g < 30) ? g : 0;
        #pragma unroll
        for (int q = 0; q < 4; ++q)
            load_split(Wf + (long)gv * II + 32 * q + 8 * lk, Bhi[t][q], Blo[t][q]);
        if (g >= 30) {                    // mask cols 30,31
            const short8v z = {0, 0, 0, 0, 0, 0, 0, 0};
            #pragma unroll
            for (int q = 0; q < 4; ++q) { Bhi[t][q] = z; Blo[t][q] = z; }
        }
        biasv[t] = bih[gv];
        const float2 wt = *(const float2*)(Wf + (long)gv * II + 128);
        wt0[t] = wt.x; wt1[t] = wt.y;
    }

    // ---- per-wave LDS tile: 16 rows x 130 f32 = 520 float4 (8320 B) ----
    __shared__ __align__(16) float lds[4][16 * II];
    float4* __restrict__ L4 = (float4*)lds[wv];
    const float* __restrict__ Lf = lds[wv];

    // wave's 64-row block is one contiguous chunk of 2080 float4
    const float4* __restrict__ src = (const float4*)X + row0 * (II / 2) / 2;
    // (row0*130/4; row0 is a multiple of 64 so this is exact)

    const long gb = (long)gru * ROWS_PER_GRU;

    // preload tile 0 (coalesced: 8 full wave-loads + 8-lane tail)
    float4 pf0, pf1, pf2, pf3, pf4, pf5, pf6, pf7, pft;
    {
        const float4* __restrict__ s = src;
        pf0 = s[lane];        pf1 = s[64 + lane];
        pf2 = s[128 + lane];  pf3 = s[192 + lane];
        pf4 = s[256 + lane];  pf5 = s[320 + lane];
        pf6 = s[384 + lane];  pf7 = s[448 + lane];
        if (lane < 8) pft = s[512 + lane];
    }

    #pragma unroll
    for (int t = 0; t < 4; ++t) {
        // stage tile t to LDS (in-wave DS ordering: prior reads done first)
        L4[lane]       = pf0;  L4[64 + lane]  = pf1;
        L4[128 + lane] = pf2;  L4[192 + lane] = pf3;
        L4[256 + lane] = pf4;  L4[320 + lane] = pf5;
        L4[384 + lane] = pf6;  L4[448 + lane] = pf7;
        if (lane < 8) L4[512 + lane] = pft;

        // prefetch tile t+1 (in flight during this tile's compute)
        if (t < 3) {
            const float4* __restrict__ s = src + 520 * (t + 1);
            pf0 = s[lane];        pf1 = s[64 + lane];
            pf2 = s[128 + lane];  pf3 = s[192 + lane];
            pf4 = s[256 + lane];  pf5 = s[320 + lane];
            pf6 = s[384 + lane];  pf7 = s[448 + lane];
            if (lane < 8) pft = s[512 + lane];
        }

        // ---- compute tile t: K=128 via 4 k-blocks, 3-term bf16 emulation ----
        f32x4 a0 = (f32x4){biasv[0], biasv[0], biasv[0], biasv[0]};
        f32x4 a1 = (f32x4){biasv[1], biasv[1], biasv[1], biasv[1]};
        #pragma unroll
        for (int q = 0; q < 4; ++q) {
            short8v ahi, alo;
            load_split(Lf + lr * II + 32 * q + 8 * lk, ahi, alo);
            a0 = __builtin_amdgcn_mfma_f32_16x16x32_bf16(ahi, Bhi[0][q], a0, 0, 0, 0);
            a0 = __builtin_amdgcn_mfma_f32_16x16x32_bf16(ahi, Blo[0][q], a0, 0, 0, 0);
            a0 = __builtin_amdgcn_mfma_f32_16x16x32_bf16(alo, Bhi[0][q], a0, 0, 0, 0);
            a1 = __builtin_amdgcn_mfma_f32_16x16x32_bf16(ahi, Bhi[1][q], a1, 0, 0, 0);
            a1 = __builtin_amdgcn_mfma_f32_16x16x32_bf16(ahi, Blo[1][q], a1, 0, 0, 0);
            a1 = __builtin_amdgcn_mfma_f32_16x16x32_bf16(alo, Bhi[1][q], a1, 0, 0, 0);
        }

        // ---- k-tail (cols 128,129 from LDS) + store ----
        // C layout: col = lr, row-in-tile = 4*lk + r (m89-verified, passed r6)
        #pragma unroll
        for (int r = 0; r < 4; ++r) {
            const int rowin = 4 * lk + r;
            const float2 xt = *(const float2*)(Lf + rowin * II + 128);
            const long rr = row0 + 16 * t + rowin;
            float* __restrict__ xo = xi + (gb + rr) * 30;
            const float v0 = a0[r] + xt.x * wt0[0] + xt.y * wt1[0];
            xo[lr] = v0;                          // g = lr (0..15)
            if (lr < 14) {
                const float v1 = a1[r] + xt.x * wt0[1] + xt.y * wt1[1];
                xo[16 + lr] = v1;                 // g = 16+lr (16..29)
            }
        }
    }
}

// ---------------- Phase 2: recurrent scan (unchanged) ----------------
__global__ __launch_bounds__(256, 4)
void gru_scan(const float* __restrict__ xi,
              const float* __restrict__ ruWhh, const float* __restrict__ rubhh,
              const float* __restrict__ enWhh, const float* __restrict__ enbhh,
              const float* __restrict__ W1, const float* __restrict__ b1,
              const float* __restrict__ W2, const float* __restrict__ b2,
              float* __restrict__ out)
{
    const int tid  = threadIdx.x;
    const int wv   = tid >> 6;
    const int lane = tid & 63;
    const int c    = lane >> 5;
    const int k    = lane & 31;
    const int kq   = (k < 10) ? k : 0;
    const int chain = (blockIdx.x * 4 + wv) * 2 + c;
    const int gru   = chain >> 11;
    const int b     = chain & (BB - 1);

    const float* __restrict__ Whh = gru ? enWhh : ruWhh;
    const float* __restrict__ bhh = gru ? enbhh : rubhh;

    float whhR[10], whhZ[10], whhN[10];
    #pragma unroll
    for (int j = 0; j < 10; ++j) {
        whhR[j] = Whh[kq * 10 + j];
        whhZ[j] = Whh[(10 + kq) * 10 + j];
        whhN[j] = Whh[(20 + kq) * 10 + j];
    }
    const float bR = bhh[kq], bZ = bhh[10 + kq], bN = bhh[20 + kq];

    __shared__ __align__(16) float lds[4][32];
    float* __restrict__ H = lds[wv] + c * 16;
    if (k < 12) H[k] = 0.f;
    float hown = 0.f;

    const float* __restrict__ xrow =
        xi + ((long)gru * ROWS_PER_GRU + (long)b * TT) * 30;

    float xR0 = xrow[kq],      xZ0 = xrow[10 + kq],  xN0 = xrow[20 + kq];
    float xR1 = xrow[30 + kq], xZ1 = xrow[40 + kq],  xN1 = xrow[50 + kq];

    for (int t = 0; t < TT; ++t) {
        const float xR = xR0, xZ = xZ0, xN = xN0;
        xR0 = xR1; xZ0 = xZ1; xN0 = xN1;
        {
            const int tn = (t + 2 < TT) ? t + 2 : TT - 1;
            const float* __restrict__ xp = xrow + (long)tn * 30;
            xR1 = xp[kq]; xZ1 = xp[10 + kq]; xN1 = xp[20 + kq];
        }

        const float4 h03 = *(const float4*)(H);
        const float4 h47 = *(const float4*)(H + 4);
        const float2 h89 = *(const float2*)(H + 8);

        float gr = bR, gz = bZ, gn = bN;
        gr = fmaf(whhR[0], h03.x, gr); gz = fmaf(whhZ[0], h03.x, gz); gn = fmaf(whhN[0], h03.x, gn);
        gr = fmaf(whhR[1], h03.y, gr); gz = fmaf(whhZ[1], h03.y, gz); gn = fmaf(whhN[1], h03.y, gn);
        gr = fmaf(whhR[2], h03.z, gr); gz = fmaf(whhZ[2], h03.z, gz); gn = fmaf(whhN[2], h03.z, gn);
        gr = fmaf(whhR[3], h03.w, gr); gz = fmaf(whhZ[3], h03.w, gz); gn = fmaf(whhN[3], h03.w, gn);
        gr = fmaf(whhR[4], h47.x, gr); gz = fmaf(whhZ[4], h47.x, gz); gn = fmaf(whhN[4], h47.x, gn);
        gr = fmaf(whhR[5], h47.y, gr); gz = fmaf(whhZ[5], h47.y, gz); gn = fmaf(whhN[5], h47.y, gn);
        gr = fmaf(whhR[6], h47.z, gr); gz = fmaf(whhZ[6], h47.z, gz); gn = fmaf(whhN[6], h47.z, gn);
        gr = fmaf(whhR[7], h47.w, gr); gz = fmaf(whhZ[7], h47.w, gz); gn = fmaf(whhN[7], h47.w, gn);
        gr = fmaf(whhR[8], h89.x, gr); gz = fmaf(whhZ[8], h89.x, gz); gn = fmaf(whhN[8], h89.x, gn);
        gr = fmaf(whhR[9], h89.y, gr); gz = fmaf(whhZ[9], h89.y, gz); gn = fmaf(whhN[9], h89.y, gn);

        const float r = sigmoidf_fast(xR + gr);
        const float z = sigmoidf_fast(xZ + gz);
        const float n = tanhf_fast(xN + r * gn);
        const float hnew = fmaf(z, hown - n, n);
        hown = hnew;
        if (k < 10) H[k] = hnew;
    }

    float val = 0.f;
    if (k < 10) {
        float v = 0.f;
        #pragma unroll
        for (int d = 0; d < 20; ++d)
            v = fmaf(W2[d], W1[d * 20 + gru * 10 + k], v);
        val = v * hown;
        if (k == 0 && gru == 0) {
            float c0 = b2[0];
            #pragma unroll
            for (int d = 0; d < 20; ++d) c0 = fmaf(W2[d], b1[d], c0);
            val += c0;
        }
    }
    val += __shfl_xor(val, 8);
    val += __shfl_xor(val, 4);
    val += __shfl_xor(val, 2);
    val += __shfl_xor(val, 1);
    if (k == 0) atomicAdd(&out[b], val);
}

// ---------------- Fallback: monolithic kernel ----------------
__global__ __launch_bounds__(256, 4)
void gru_fused(const float* __restrict__ ru, const float* __restrict__ en,
               const float* __restrict__ ruWih, const float* __restrict__ ruWhh,
               const float* __restrict__ rubih, const float* __restrict__ rubhh,
               const float* __restrict__ enWih, const float* __restrict__ enWhh,
               const float* __restrict__ enbih, const float* __restrict__ enbhh,
               const float* __restrict__ W1, const float* __restrict__ b1,
               const float* __restrict__ W2, const float* __restrict__ b2,
               float* __restrict__ out)
{
    const int tid  = threadIdx.x;
    const int wv   = tid >> 6;
    const int lane = tid & 63;
    const int g    = lane & 31;
    const int h    = lane >> 5;
    const int wid  = blockIdx.x * 4 + wv;
    const int gru  = wid >> 11;
    const int b    = wid & (BB - 1);

    const float* __restrict__ x   = gru ? en    : ru;
    const float* __restrict__ Wih = gru ? enWih : ruWih;
    const float* __restrict__ Whh = gru ? enWhh : ruWhh;
    const float* __restrict__ bih = gru ? enbih : rubih;
    const float* __restrict__ bhh = gru ? enbhh : rubhh;

    __shared__ __align__(16) float lds[4][176];
    float* __restrict__ X    = lds[wv];
    float* __restrict__ PRE  = X + 132;
    float* __restrict__ Hbuf = X + 164;

    const int gq = (g < 30) ? g : 0;
    float wih[64];
    #pragma unroll
    for (int j = 0; j < 64; ++j) wih[j] = Wih[gq * II + h * 64 + j];
    const float w_e = Wih[gq * II + 128 + h];
    float whh[10];
    #pragma unroll
    for (int k = 0; k < 10; ++k) whh[k] = Whh[gq * 10 + k];
    const float bihg = bih[gq];
    const float bhhg = bhh[gq];

    if (lane < 12) Hbuf[lane] = 0.f;
    float hown = 0.f;

    const float* __restrict__ xrow = x + (size_t)b * (TT * II);
    float xa = xrow[lane];
    float xb = xrow[64 + lane];
    float xc = (lane < 2) ? xrow[128 + lane] : 0.f;

    for (int t = 0; t < TT; ++t) {
        X[lane] = xa;
        X[64 + lane] = xb;
        if (lane < 2) X[128 + lane] = xc;
        {
            const int tn = (t < TT - 1) ? t + 1 : t;
            const float* __restrict__ xn = xrow + (size_t)tn * II;
            xa = xn[lane];
            xb = xn[64 + lane];
            xc = (lane < 2) ? xn[128 + lane] : 0.f;
        }
        const float4 h03 = *(const float4*)(Hbuf);
        const float4 h47 = *(const float4*)(Hbuf + 4);
        const float2 h89 = *(const float2*)(Hbuf + 8);
        float gh0 = fmaf(whh[0], h03.x, bhhg);
        float gh1 = whh[1] * h03.y;
        gh0 = fmaf(whh[2], h03.z, gh0);
        gh1 = fmaf(whh[3], h03.w, gh1);
        gh0 = fmaf(whh[4], h47.x, gh0);
        gh1 = fmaf(whh[5], h47.y, gh1);
        gh0 = fmaf(whh[6], h47.z, gh0);
        gh1 = fmaf(whh[7], h47.w, gh1);
        gh0 = fmaf(whh[8], h89.x, gh0);
        gh1 = fmaf(whh[9], h89.y, gh1);
        const float gh = gh0 + gh1;

        float s0 = 0.f, s1 = 0.f, s2 = 0.f, s3 = 0.f;
        const float4* __restrict__ xb4 = (const float4*)(X + h * 64);
        #pragma unroll
        for (int c = 0; c < 16; ++c) {
            const float4 v = xb4[c];
            s0 = fmaf(wih[4 * c + 0], v.x, s0);
            s1 = fmaf(wih[4 * c + 1], v.y, s1);
            s2 = fmaf(wih[4 * c + 2], v.z, s2);
            s3 = fmaf(wih[4 * c + 3], v.w, s3);
        }
        float s = (s0 + s1) + (s2 + s3);
        s = fmaf(w_e, X[128 + h], s);
        s += __shfl_xor(s, 32);

        const float xiv = s + bihg;
        const float pre = xiv + gh;
        if (lane < 30) PRE[lane] = pre;
        const float rpre = PRE[(g - 20) & 31];
        const float zpre = PRE[(g - 10) & 31];
        const float r = sigmoidf_fast(rpre);
        const float z = sigmoidf_fast(zpre);
        const float n = tanhf_fast(xiv + r * gh);
        const float hnew = (1.f - z) * n + z * hown;
        hown = hnew;
        if (lane >= 20 && lane < 30) Hbuf[lane - 20] = hnew;
    }

    float val = 0.f;
    if (lane < 10) {
        const float hk = Hbuf[lane];
        float v = 0.f;
        #pragma unroll
        for (int d = 0; d < 20; ++d)
            v = fmaf(W2[d], W1[d * 20 + gru * 10 + lane], v);
        val = v * hk;
        if (lane == 0 && gru == 0) {
            float c0 = b2[0];
            #pragma unroll
            for (int d = 0; d < 20; ++d) c0 = fmaf(W2[d], b1[d], c0);
            val += c0;
        }
    }
    #pragma unroll
    for (int o = 32; o > 0; o >>= 1) val += __shfl_xor(val, o);
    if (lane == 0) atomicAdd(&out[b], val);
}

extern "C" void kernel_launch(void* const* d_in, const int* in_sizes, int n_in,
                              void* d_out, int out_size, void* d_ws, size_t ws_size,
                              hipStream_t stream) {
    (void)in_sizes; (void)n_in;
    const float* ru    = (const float*)d_in[0];
    const float* en    = (const float*)d_in[1];
    const float* ruWih = (const float*)d_in[2];
    const float* ruWhh = (const float*)d_in[3];
    const float* rubih = (const float*)d_in[4];
    const float* rubhh = (const float*)d_in[5];
    const float* enWih = (const float*)d_in[6];
    const float* enWhh = (const float*)d_in[7];
    const float* enbih = (const float*)d_in[8];
    const float* enbhh = (const float*)d_in[9];
    const float* W1    = (const float*)d_in[10];
    const float* b1    = (const float*)d_in[11];
    const float* W2    = (const float*)d_in[12];
    const float* b2    = (const float*)d_in[13];
    float* out = (float*)d_out;

    hipMemsetAsync(d_out, 0, (size_t)out_size * sizeof(float), stream);

    const size_t xi_bytes = (size_t)ROWS_TOTAL * 30 * sizeof(float);  // ~63 MB
    if (ws_size >= xi_bytes) {
        float* xi = (float*)d_ws;
        xi_gemm<<<dim3(2048), dim3(256), 0, stream>>>(
            ru, en, ruWih, rubih, enWih, enbih, xi);
        gru_scan<<<dim3(512), dim3(256), 0, stream>>>(
            xi, ruWhh, rubhh, enWhh, enbhh, W1, b1, W2, b2, out);
    } else {
        gru_fused<<<dim3(1024), dim3(256), 0, stream>>>(
            ru, en, ruWih, ruWhh, rubih, rubhh,
            enWih, enWhh, enbih, enbhh, W1, b1, W2, b2, out);
    }
}